// Round 1
// baseline (288.372 us; speedup 1.0000x reference)
//
#include <hip/hip_runtime.h>
#include <hip/hip_bf16.h>
#include <stdint.h>

#define T_TOK 4096
#define NEXP  8
#define HDIM  1024
#define IDIM  2048
#define TOPK  2

#define BM 128
#define BK 64

typedef __attribute__((ext_vector_type(8))) short short8;
typedef __attribute__((ext_vector_type(4))) float f32x4;

__device__ __forceinline__ unsigned short f2bf(float f) {
    union { float f; unsigned int u; } v; v.f = f;
    unsigned int u = v.u;
    unsigned int r = (u + 0x7fffu + ((u >> 16) & 1u)) >> 16;
    return (unsigned short)r;
}

__device__ __forceinline__ void gload_lds16(const void* g, void* l) {
    __builtin_amdgcn_global_load_lds(
        (const __attribute__((address_space(1))) unsigned int*)g,
        (__attribute__((address_space(3))) unsigned int*)l,
        16, 0, 0);
}

// ---------------- routing ----------------

__global__ void init_k(int* cnt) {
    if (threadIdx.x < NEXP) cnt[threadIdx.x] = 0;
}

__global__ void router_k(const float* __restrict__ logits, int* __restrict__ cnt,
                         int* __restrict__ eids, float* __restrict__ ews) {
    int t = blockIdx.x * blockDim.x + threadIdx.x;
    if (t >= T_TOK) return;
    const float4* lp = (const float4*)(logits + (size_t)t * NEXP);
    float4 a = lp[0], b = lp[1];
    float l[NEXP] = {a.x, a.y, a.z, a.w, b.x, b.y, b.z, b.w};
    int e0 = 0; float b0 = l[0];
    #pragma unroll
    for (int e = 1; e < NEXP; ++e) if (l[e] > b0) { b0 = l[e]; e0 = e; }
    int e1 = -1; float b1 = -1e30f;
    #pragma unroll
    for (int e = 0; e < NEXP; ++e) { if (e == e0) continue; if (l[e] > b1) { b1 = l[e]; e1 = e; } }
    // top-2 of softmax renormalized == softmax over top-2 logits
    float tt = __expf(b1 - b0);
    float w0 = 1.0f / (1.0f + tt);
    float w1 = 1.0f - w0;
    eids[2 * t] = e0; eids[2 * t + 1] = e1;
    ews[2 * t] = w0;  ews[2 * t + 1] = w1;
    atomicAdd(&cnt[e0], 1); atomicAdd(&cnt[e1], 1);
}

__global__ void offs_k(const int* __restrict__ cnt, int* __restrict__ offs, int* __restrict__ cursor) {
    if (threadIdx.x == 0) {
        int s = 0;
        for (int e = 0; e < NEXP; ++e) { offs[e] = s; cursor[e] = s; s += cnt[e]; }
        offs[NEXP] = s;
    }
}

__global__ void scatter_k(const int* __restrict__ eids, const float* __restrict__ ews,
                          int* __restrict__ cursor, int* __restrict__ tokid,
                          float* __restrict__ tokw, int* __restrict__ pos) {
    int t = blockIdx.x * blockDim.x + threadIdx.x;
    if (t >= T_TOK) return;
    #pragma unroll
    for (int k = 0; k < TOPK; ++k) {
        int e = eids[2 * t + k];
        int p = atomicAdd(&cursor[e], 1);
        tokid[p] = t; tokw[p] = ews[2 * t + k]; pos[2 * t + k] = p;
    }
}

// ---------------- fp32 -> bf16 convert ----------------

__global__ void cvt_k(const float* __restrict__ in, unsigned short* __restrict__ out, int n8) {
    int i = blockIdx.x * blockDim.x + threadIdx.x;
    if (i >= n8) return;
    const float4* p = (const float4*)(in + (size_t)i * 8);
    float4 a = p[0], b = p[1];
    union { unsigned short s[8]; short8 v; } r;
    r.s[0] = f2bf(a.x); r.s[1] = f2bf(a.y); r.s[2] = f2bf(a.z); r.s[3] = f2bf(a.w);
    r.s[4] = f2bf(b.x); r.s[5] = f2bf(b.y); r.s[6] = f2bf(b.z); r.s[7] = f2bf(b.w);
    *(short8*)(out + (size_t)i * 8) = r.v;
}

// ---------------- GEMM1: h = silu(x@W1^T) * (x@W3^T), gate/up fused ----------------
// grid (IDIM/BM=16, T_TOK/BM=32, NEXP), block 256

__global__ __launch_bounds__(256, 2) void gemm1_k(
    const unsigned short* __restrict__ xb,     // [T][H] bf16
    const unsigned short* __restrict__ w13b,   // [E][2I][H] bf16
    const int* __restrict__ tokid,
    const int* __restrict__ offs,
    unsigned short* __restrict__ hbuf)         // [T*K][I] bf16
{
    const int e = blockIdx.z;
    const int off_e = offs[e];
    const int cnt_e = offs[e + 1] - off_e;
    const int mt = blockIdx.y;
    if (mt * BM >= cnt_e) return;
    const int nt = blockIdx.x;

    __shared__ __align__(16) unsigned short As[BM * BK];
    __shared__ __align__(16) unsigned short Bg[BM * BK];
    __shared__ __align__(16) unsigned short Bu[BM * BK];

    const int tid = threadIdx.x;
    const int w = tid >> 6, lane = tid & 63;

    const char* aSrc[4]; const char* gSrc[4]; const char* uSrc[4];
    int ldsOff[4]; int aOk[4];
    #pragma unroll
    for (int i = 0; i < 4; ++i) {
        int S = (i * 4 + w) * 64 + lane;            // 16B slot index, 0..1023
        int row = S >> 3;
        int ko = (S & 7) ^ (row & 7);               // inverse-swizzled global ko
        ldsOff[i] = (i * 4 + w) * 512;              // ushort units (1KB per wave-chunk)
        int lrow = mt * BM + row;
        aOk[i] = (lrow < cnt_e);
        int rr = off_e + (aOk[i] ? lrow : 0);
        int tok = tokid[rr];
        aSrc[i] = (const char*)(xb + (size_t)tok * HDIM + ko * 8);
        gSrc[i] = (const char*)(w13b + (size_t)e * 2 * IDIM * HDIM + (size_t)(nt * BM + row) * HDIM + ko * 8);
        uSrc[i] = (const char*)(w13b + (size_t)e * 2 * IDIM * HDIM + (size_t)(IDIM + nt * BM + row) * HDIM + ko * 8);
    }

    const int wm = w >> 1, wn = w & 1;
    f32x4 g[4][4], u[4][4];
    const f32x4 z4 = {0.f, 0.f, 0.f, 0.f};
    #pragma unroll
    for (int m = 0; m < 4; ++m)
        #pragma unroll
        for (int n = 0; n < 4; ++n) { g[m][n] = z4; u[m][n] = z4; }

    const int KT = HDIM / BK; // 16
    for (int kt = 0; kt < KT; ++kt) {
        #pragma unroll
        for (int i = 0; i < 4; ++i) {
            if (aOk[i]) gload_lds16(aSrc[i] + kt * (BK * 2), &As[ldsOff[i]]);
            gload_lds16(gSrc[i] + kt * (BK * 2), &Bg[ldsOff[i]]);
            gload_lds16(uSrc[i] + kt * (BK * 2), &Bu[ldsOff[i]]);
        }
        __syncthreads();
        #pragma unroll
        for (int kk = 0; kk < 2; ++kk) {
            short8 av[4], bgv[4], buv[4];
            int ko = kk * 4 + (lane >> 4);
            #pragma unroll
            for (int m = 0; m < 4; ++m) {
                int row = wm * 64 + m * 16 + (lane & 15);
                int idx = row * BK + ((ko ^ (row & 7)) * 8);
                av[m] = *(const short8*)(As + idx);
            }
            #pragma unroll
            for (int n = 0; n < 4; ++n) {
                int row = wn * 64 + n * 16 + (lane & 15);
                int idx = row * BK + ((ko ^ (row & 7)) * 8);
                bgv[n] = *(const short8*)(Bg + idx);
                buv[n] = *(const short8*)(Bu + idx);
            }
            #pragma unroll
            for (int m = 0; m < 4; ++m)
                #pragma unroll
                for (int n = 0; n < 4; ++n) {
                    g[m][n] = __builtin_amdgcn_mfma_f32_16x16x32_bf16(av[m], bgv[n], g[m][n], 0, 0, 0);
                    u[m][n] = __builtin_amdgcn_mfma_f32_16x16x32_bf16(av[m], buv[n], u[m][n], 0, 0, 0);
                }
        }
        __syncthreads();
    }

    // epilogue: h = silu(gate) * up -> bf16
    #pragma unroll
    for (int m = 0; m < 4; ++m) {
        #pragma unroll
        for (int i = 0; i < 4; ++i) {
            int lrow = wm * 64 + m * 16 + ((lane >> 4) * 4) + i;
            if (mt * BM + lrow >= cnt_e) continue;
            size_t rbase = (size_t)(off_e + mt * BM + lrow) * IDIM;
            #pragma unroll
            for (int n = 0; n < 4; ++n) {
                int col = nt * BM + wn * 64 + n * 16 + (lane & 15);
                float gv = g[m][n][i];
                float uv = u[m][n][i];
                float hv = gv / (1.0f + __expf(-gv)) * uv;
                hbuf[rbase + col] = f2bf(hv);
            }
        }
    }
}

// ---------------- GEMM2: pout = h @ W2^T ----------------
// grid (HDIM/BM=8, T_TOK/BM=32, NEXP), block 256

__global__ __launch_bounds__(256, 2) void gemm2_k(
    const unsigned short* __restrict__ hbuf,   // [T*K][I] bf16
    const unsigned short* __restrict__ w2b,    // [E][H][I] bf16
    const int* __restrict__ offs,
    float* __restrict__ pout)                  // [T*K][H] f32
{
    const int e = blockIdx.z;
    const int off_e = offs[e];
    const int cnt_e = offs[e + 1] - off_e;
    const int mt = blockIdx.y;
    if (mt * BM >= cnt_e) return;
    const int nt = blockIdx.x;

    __shared__ __align__(16) unsigned short As[BM * BK];
    __shared__ __align__(16) unsigned short Bs[BM * BK];

    const int tid = threadIdx.x;
    const int w = tid >> 6, lane = tid & 63;

    const char* aSrc[4]; const char* bSrc[4];
    int ldsOff[4]; int aOk[4];
    #pragma unroll
    for (int i = 0; i < 4; ++i) {
        int S = (i * 4 + w) * 64 + lane;
        int row = S >> 3;
        int ko = (S & 7) ^ (row & 7);
        ldsOff[i] = (i * 4 + w) * 512;
        int lrow = mt * BM + row;
        aOk[i] = (lrow < cnt_e);
        int rr = off_e + (aOk[i] ? lrow : 0);
        aSrc[i] = (const char*)(hbuf + (size_t)rr * IDIM + ko * 8);
        bSrc[i] = (const char*)(w2b + (size_t)e * HDIM * IDIM + (size_t)(nt * BM + row) * IDIM + ko * 8);
    }

    const int wm = w >> 1, wn = w & 1;
    f32x4 acc[4][4];
    const f32x4 z4 = {0.f, 0.f, 0.f, 0.f};
    #pragma unroll
    for (int m = 0; m < 4; ++m)
        #pragma unroll
        for (int n = 0; n < 4; ++n) acc[m][n] = z4;

    const int KT = IDIM / BK; // 32
    for (int kt = 0; kt < KT; ++kt) {
        #pragma unroll
        for (int i = 0; i < 4; ++i) {
            if (aOk[i]) gload_lds16(aSrc[i] + kt * (BK * 2), &As[ldsOff[i]]);
            gload_lds16(bSrc[i] + kt * (BK * 2), &Bs[ldsOff[i]]);
        }
        __syncthreads();
        #pragma unroll
        for (int kk = 0; kk < 2; ++kk) {
            short8 av[4], bv[4];
            int ko = kk * 4 + (lane >> 4);
            #pragma unroll
            for (int m = 0; m < 4; ++m) {
                int row = wm * 64 + m * 16 + (lane & 15);
                int idx = row * BK + ((ko ^ (row & 7)) * 8);
                av[m] = *(const short8*)(As + idx);
            }
            #pragma unroll
            for (int n = 0; n < 4; ++n) {
                int row = wn * 64 + n * 16 + (lane & 15);
                int idx = row * BK + ((ko ^ (row & 7)) * 8);
                bv[n] = *(const short8*)(Bs + idx);
            }
            #pragma unroll
            for (int m = 0; m < 4; ++m)
                #pragma unroll
                for (int n = 0; n < 4; ++n)
                    acc[m][n] = __builtin_amdgcn_mfma_f32_16x16x32_bf16(av[m], bv[n], acc[m][n], 0, 0, 0);
        }
        __syncthreads();
    }

    #pragma unroll
    for (int m = 0; m < 4; ++m) {
        #pragma unroll
        for (int i = 0; i < 4; ++i) {
            int lrow = wm * 64 + m * 16 + ((lane >> 4) * 4) + i;
            if (mt * BM + lrow >= cnt_e) continue;
            size_t rbase = (size_t)(off_e + mt * BM + lrow) * HDIM;
            #pragma unroll
            for (int n = 0; n < 4; ++n) {
                int col = nt * BM + wn * 64 + n * 16 + (lane & 15);
                pout[rbase + col] = acc[m][n][i];
            }
        }
    }
}

// ---------------- combine: out[t] = w0*pout[p0] + w1*pout[p1] ----------------

__global__ void combine_k(const float* __restrict__ pout, const int* __restrict__ pos,
                          const float* __restrict__ tokw, float* __restrict__ out) {
    int idx = blockIdx.x * blockDim.x + threadIdx.x;   // T*H/4 threads
    int t = idx >> 8;           // H/4 = 256 float4 per row
    int c4 = idx & 255;
    int p0 = pos[2 * t], p1 = pos[2 * t + 1];
    float w0 = tokw[p0], w1 = tokw[p1];
    float4 a = ((const float4*)(pout + (size_t)p0 * HDIM))[c4];
    float4 b = ((const float4*)(pout + (size_t)p1 * HDIM))[c4];
    float4 o;
    o.x = w0 * a.x + w1 * b.x;
    o.y = w0 * a.y + w1 * b.y;
    o.z = w0 * a.z + w1 * b.z;
    o.w = w0 * a.w + w1 * b.w;
    ((float4*)out)[idx] = o;
}

// ---------------- launch ----------------

extern "C" void kernel_launch(void* const* d_in, const int* in_sizes, int n_in,
                              void* d_out, int out_size, void* d_ws, size_t ws_size,
                              hipStream_t stream) {
    const float* x      = (const float*)d_in[0];
    const float* logits = (const float*)d_in[1];
    const float* w13    = (const float*)d_in[2];
    const float* w2     = (const float*)d_in[3];
    float* out = (float*)d_out;

    char* ws = (char*)d_ws;
    size_t off = 0;
    auto carve = [&](size_t bytes) -> void* {
        void* p = ws + off;
        off = (off + bytes + 255) & ~(size_t)255;
        return p;
    };
    int*   cnt    = (int*)carve(NEXP * 4);
    int*   offs   = (int*)carve((NEXP + 1) * 4);
    int*   cursor = (int*)carve(NEXP * 4);
    int*   eids   = (int*)carve((size_t)T_TOK * 2 * 4);
    float* ews    = (float*)carve((size_t)T_TOK * 2 * 4);
    int*   tokid  = (int*)carve((size_t)(T_TOK * TOPK + 256) * 4);
    float* tokw   = (float*)carve((size_t)T_TOK * TOPK * 4);
    int*   pos    = (int*)carve((size_t)T_TOK * TOPK * 4);
    unsigned short* xb   = (unsigned short*)carve((size_t)T_TOK * HDIM * 2);
    unsigned short* w13b = (unsigned short*)carve((size_t)NEXP * 2 * IDIM * HDIM * 2);
    unsigned short* w2b  = (unsigned short*)carve((size_t)NEXP * HDIM * IDIM * 2);
    unsigned short* hbuf = (unsigned short*)carve((size_t)T_TOK * TOPK * IDIM * 2);
    float* pout = (float*)carve((size_t)T_TOK * TOPK * HDIM * 4);

    init_k<<<1, 64, 0, stream>>>(cnt);
    router_k<<<T_TOK / 256, 256, 0, stream>>>(logits, cnt, eids, ews);
    offs_k<<<1, 1, 0, stream>>>(cnt, offs, cursor);
    scatter_k<<<T_TOK / 256, 256, 0, stream>>>(eids, ews, cursor, tokid, tokw, pos);

    cvt_k<<<(T_TOK * HDIM / 8) / 256, 256, 0, stream>>>(x, xb, T_TOK * HDIM / 8);
    cvt_k<<<(NEXP * 2 * IDIM * HDIM / 8) / 256, 256, 0, stream>>>(w13, w13b, NEXP * 2 * IDIM * HDIM / 8);
    cvt_k<<<(NEXP * HDIM * IDIM / 8) / 256, 256, 0, stream>>>(w2, w2b, NEXP * HDIM * IDIM / 8);

    gemm1_k<<<dim3(IDIM / BM, T_TOK / BM, NEXP), 256, 0, stream>>>(xb, w13b, tokid, offs, hbuf);
    gemm2_k<<<dim3(HDIM / BM, T_TOK / BM, NEXP), 256, 0, stream>>>(hbuf, w2b, offs, pout);

    combine_k<<<(T_TOK * HDIM / 4) / 256, 256, 0, stream>>>(pout, pos, tokw, out);
}